// Round 14
// baseline (419.953 us; speedup 1.0000x reference)
//
#include <hip/hip_runtime.h>
#include <hip/hip_fp16.h>

#define N_NODES 100000
#define N_EDGES 1600000
#define N_BUCKETS 256
#define BUCKET_NODES 391      // 256*391 = 100096 >= N_NODES
#define BKT_BLOCKS 512
#define CAP_E 8192            // raw edges per bucket: mean 6250
#define CAP_C 12288           // padded(8) col slots per bucket: mean ~7800
#define DUMMY N_NODES         // zero feature row
#define CH_ELE ((size_t)(N_NODES + 8) * 16)   // u16 elements per feature chunk

typedef unsigned short u16;
typedef _Float16 f16x8 __attribute__((ext_vector_type(8)));
typedef float f32x4 __attribute__((ext_vector_type(4)));

__device__ __forceinline__ u16 f2h(float f) {
    return __half_as_ushort(__float2half_rn(f));
}

__device__ __forceinline__ void acc8(float* acc, uint4 q) {
    unsigned v[4] = {q.x, q.y, q.z, q.w};
#pragma unroll
    for (int i = 0; i < 4; ++i) {
        __half2 h = *reinterpret_cast<__half2*>(&v[i]);
        float2 f = __half22float2(h);
        acc[2 * i] += f.x;
        acc[2 * i + 1] += f.y;
    }
}

// ---- phase 1: bucket edges into CONTIGUOUS per-bucket runs. ----
__global__ __launch_bounds__(256) void k_bucket(const int* __restrict__ src,
                                                const int* __restrict__ dst,
                                                int* __restrict__ btot,
                                                int* __restrict__ ebuf) {
    __shared__ int cnt[N_BUCKETS], base_s[N_BUCKETS];
    const int CS = N_EDGES / BKT_BLOCKS;  // 3125
    int t = threadIdx.x;
    int beg = blockIdx.x * CS, end = beg + CS;
    for (int i = t; i < N_BUCKETS; i += 256) cnt[i] = 0;
    __syncthreads();
    for (int e = beg + t; e < end; e += 256)
        atomicAdd(&cnt[(unsigned)dst[e] / BUCKET_NODES], 1);
    __syncthreads();
    for (int i = t; i < N_BUCKETS; i += 256) {
        base_s[i] = atomicAdd(&btot[i], cnt[i]);
        cnt[i] = 0;  // reuse as local cursor
    }
    __syncthreads();
    for (int e = beg + t; e < end; e += 256) {
        int d = dst[e], s = src[e];
        int b = (unsigned)d / BUCKET_NODES;
        int l = atomicAdd(&cnt[b], 1);
        ebuf[b * CAP_E + base_s[b] + l] = s | ((d - b * BUCKET_NODES) << 17);
    }
}

// ---- phase 2: per-bucket LDS bin; PAD-8 rows; col = byte offset (node*32)
//      within a feature chunk; fused CHUNKED xs(fp16) = z*dinv. ----
__global__ __launch_bounds__(1024) void k_build(const int* __restrict__ btot,
                                                const int* __restrict__ ebuf,
                                                int* __restrict__ col,
                                                int2* __restrict__ rowinfo,
                                                float* __restrict__ dinv,
                                                const float* __restrict__ z,
                                                u16* __restrict__ xs,
                                                u16* __restrict__ xs_other) {
    __shared__ int deg[BUCKET_NODES];
    __shared__ int cur[BUCKET_NODES];
    __shared__ int sm[512];
    __shared__ int cls[CAP_C];
    int b = blockIdx.x, t = threadIdx.x;
    int nb = b * BUCKET_NODES;
    int nn = N_NODES - nb < BUCKET_NODES ? N_NODES - nb : BUCKET_NODES;
    int ne = btot[b];
    const int* eb = ebuf + b * CAP_E;

    for (int i = t; i < BUCKET_NODES; i += 1024) deg[i] = 0;
    __syncthreads();
    for (int e = t; e < ne; e += 1024) atomicAdd(&deg[eb[e] >> 17], 1);
    __syncthreads();

    // pad-to-8 lengths, inclusive Hillis-Steele scan over 512 slots (nn<512)
    int v = (t < nn) ? ((deg[t] + 7) & ~7) : 0;
    if (t < 512) sm[t] = v;
    __syncthreads();
    for (int off = 1; off < 512; off <<= 1) {
        int u = (t >= off && t < 512) ? sm[t - off] : 0;
        __syncthreads();
        if (t < 512) sm[t] += u;
        __syncthreads();
    }
    int total = sm[511];
    int colbase = b * CAP_C;
    if (t < nn) {
        int off0 = sm[t] - v;
        cur[t] = off0;
        rowinfo[nb + t] = make_int2(colbase + off0, v);
        dinv[nb + t] = rsqrtf((float)deg[t] + 1.0f);
    }
    __syncthreads();
    for (int i = t; i < total; i += 1024) cls[i] = DUMMY << 5;  // pads pre-filled
    __syncthreads();
    for (int e = t; e < ne; e += 1024) {
        int pe = eb[e];
        int l = atomicAdd(&cur[pe >> 17], 1);
        cls[l] = (pe & 0x1FFFF) << 5;  // byte offset of src chunk-row (32 B)
    }
    __syncthreads();
    for (int i = t; i < total; i += 1024) col[colbase + i] = cls[i];
    if (t < 16) col[colbase + total + t] = DUMMY << 5;  // guard

    // fused scale: CHUNKED xs(fp16) = z * dinv; chunk c holds features [16c,16c+16)
    const float4* zz = (const float4*)(z + (size_t)nb * 64);
    for (int i = t; i < nn * 16; i += 1024) {
        float4 vv = zz[i];
        int node = nb + (i >> 4);
        int c = (i & 15) >> 2;     // feature chunk
        int q = i & 3;             // 4-feature group within chunk row
        float dd = rsqrtf((float)deg[i >> 4] + 1.0f);
        unsigned p0 = (unsigned)f2h(vv.x * dd) | ((unsigned)f2h(vv.y * dd) << 16);
        unsigned p1 = (unsigned)f2h(vv.z * dd) | ((unsigned)f2h(vv.w * dd) << 16);
        *(uint2*)(xs + (size_t)c * CH_ELE + (size_t)node * 16 + q * 4) = make_uint2(p0, p1);
    }
    if (b == 0 && t < 16) {  // zero dummy chunk-rows of both feature buffers
        int c = t >> 2, q = t & 3;
        *(uint2*)(xs + (size_t)c * CH_ELE + (size_t)DUMMY * 16 + q * 4) = make_uint2(0, 0);
        *(uint2*)(xs_other + (size_t)c * CH_ELE + (size_t)DUMMY * 16 + q * 4) = make_uint2(0, 0);
    }
}

// ---- phased gather aggregation: for chunk c (3.2 MB, L2-resident), compute
//      h[n][16c..16c+16) = fp16( dinv[n]*(sum_s xs_c[s] + xs_c[n]) ).
//      Dual node per wave (lanes 0-31 node0, 32-63 node1); slot = (lane&31)>>1,
//      half = lane&1 (8 features, one uint4 gather). 16 slots/node/iter. ----
__global__ __launch_bounds__(256) void k_agg(const int2* __restrict__ rowinfo,
                                             const int* __restrict__ col,
                                             const float* __restrict__ dinv,
                                             const u16* __restrict__ xs,
                                             u16* __restrict__ h) {
    const int lane = threadIdx.x & 63;
    const int g = lane >> 5;          // node within pair
    const int slot = (lane & 31) >> 1;
    const int hh = lane & 1;          // which 8-feature half of the chunk
    int wave = (blockIdx.x * blockDim.x + threadIdx.x) >> 6;
    int nwaves = (gridDim.x * blockDim.x) >> 6;

    for (int c = 0; c < 4; ++c) {
        const char* xc = (const char*)(xs + (size_t)c * CH_ELE);
        for (int n0 = wave * 2; n0 < N_NODES; n0 += nwaves * 2) {
            int u0 = __builtin_amdgcn_readfirstlane(n0);
            int u1 = u0 + 1;  // N_NODES even -> always valid
            int2 r0 = rowinfo[u0];
            int2 r1 = rowinfo[u1];
            int rbase = g ? r1.x : r0.x;
            int y = g ? r1.y : r0.y;
            int it = y >> 4;
            int it0 = r0.y >> 4, it1 = r1.y >> 4;
            int itm = it0 > it1 ? it0 : it1;

            float acc[8] = {0.f, 0.f, 0.f, 0.f, 0.f, 0.f, 0.f, 0.f};
            for (int r = 0; r < itm; ++r) {
                int oo = (r < it) ? (r << 4) : 0;
                int coff = col[rbase + oo + slot];
                uint4 q = *(const uint4*)(xc + (unsigned)coff + hh * 16);
                if (r < it) acc8(acc, q);
            }
            int tl = (y >> 3) & 1;
            if (((r0.y | r1.y) >> 3) & 1) {  // 8-slot tail for either node
                int coff = col[rbase + (it << 4) + (slot & 7)];
                uint4 q = *(const uint4*)(xc + (unsigned)coff + hh * 16);
                if (tl && slot < 8) acc8(acc, q);
            }

            // butterfly over 16 slot-pairs within each 32-lane group
#pragma unroll
            for (int m = 2; m <= 16; m <<= 1) {
#pragma unroll
                for (int j = 0; j < 8; ++j) acc[j] += __shfl_xor(acc[j], m, 64);
            }

            // self chunk-row + dinv scale (all lanes; only 2 lanes/group store)
            int un = g ? u1 : u0;
            uint4 qs = *(const uint4*)(xc + (size_t)un * 32 + hh * 16);
            float s[8] = {0.f, 0.f, 0.f, 0.f, 0.f, 0.f, 0.f, 0.f};
            acc8(s, qs);
            float dv = dinv[un];
            uint4 p;
            u16* pp = (u16*)&p;
#pragma unroll
            for (int j = 0; j < 8; ++j) pp[j] = f2h((acc[j] + s[j]) * dv);
            if ((lane & 31) < 2)
                *(uint4*)(h + (size_t)un * 64 + c * 16 + hh * 8) = p;
        }
    }
}

// ---- MFMA matvec: out = epi( h @ W + b ), 16-row chunks per wave.
//      Hidden layers write CHUNKED fp16 (feeds next agg); final writes fp32. ----
__global__ __launch_bounds__(256) void k_mv(const u16* __restrict__ h,
                                            const float* __restrict__ W,
                                            const float* __restrict__ bias,
                                            const float* __restrict__ dinv,
                                            u16* __restrict__ outh,
                                            float* __restrict__ outf, int hidden) {
    const int lane = threadIdx.x & 63;
    const int quad = lane >> 4;
    const int l16 = lane & 15;

    f16x8 bfr[4][2];
#pragma unroll
    for (int t = 0; t < 4; ++t)
#pragma unroll
        for (int c = 0; c < 2; ++c)
#pragma unroll
            for (int j = 0; j < 8; ++j)
                bfr[t][c][j] = (_Float16)W[(quad * 8 + 32 * c + j) * 64 + l16 + 16 * t];
    float bv[4];
#pragma unroll
    for (int t = 0; t < 4; ++t) bv[t] = bias[l16 + 16 * t];

    int wave = (blockIdx.x * blockDim.x + threadIdx.x) >> 6;
    int nwaves = (gridDim.x * blockDim.x) >> 6;
    for (int chunk = wave; chunk < N_NODES / 16; chunk += nwaves) {
        int row0 = chunk * 16;
        const u16* hb = h + (size_t)row0 * 64;
        union { uint4 u; f16x8 f; } a0, a1;
        a0.u = *(const uint4*)(hb + l16 * 64 + quad * 8);
        a1.u = *(const uint4*)(hb + l16 * 64 + quad * 8 + 32);

        f32x4 acc[4] = {{0.f, 0.f, 0.f, 0.f}, {0.f, 0.f, 0.f, 0.f},
                        {0.f, 0.f, 0.f, 0.f}, {0.f, 0.f, 0.f, 0.f}};
#pragma unroll
        for (int t = 0; t < 4; ++t) {
            acc[t] = __builtin_amdgcn_mfma_f32_16x16x32_f16(a0.f, bfr[t][0], acc[t], 0, 0, 0);
            acc[t] = __builtin_amdgcn_mfma_f32_16x16x32_f16(a1.f, bfr[t][1], acc[t], 0, 0, 0);
        }
        float dv[4];
#pragma unroll
        for (int r = 0; r < 4; ++r) dv[r] = dinv[row0 + quad * 4 + r];
#pragma unroll
        for (int r = 0; r < 4; ++r) {
            int row = row0 + quad * 4 + r;
#pragma unroll
            for (int t = 0; t < 4; ++t) {
                float o = acc[t][r] + bv[t];
                if (hidden) {
                    o = fmaxf(o, 0.f) * dv[r];
                    // chunked dest: feature n = l16+16t -> chunk t, offset l16
                    outh[(size_t)t * CH_ELE + (size_t)row * 16 + l16] = f2h(o);
                } else {
                    outf[(size_t)row * 64 + l16 + 16 * t] = o;
                }
            }
        }
    }
}

extern "C" void kernel_launch(void* const* d_in, const int* in_sizes, int n_in,
                              void* d_out, int out_size, void* d_ws, size_t ws_size,
                              hipStream_t stream) {
    const float* z  = (const float*)d_in[0];
    const int* src  = (const int*)d_in[1];
    const int* dst  = (const int*)d_in[2];
    const float* W1 = (const float*)d_in[3];
    const float* b1 = (const float*)d_in[4];
    const float* W2 = (const float*)d_in[5];
    const float* b2 = (const float*)d_in[6];
    const float* W3 = (const float*)d_in[7];
    const float* b3 = (const float*)d_in[8];
    float* out = (float*)d_out;

    char* p = (char*)d_ws;
    float* dinv    = (float*)p;  p += (size_t)512 << 10;
    int2*  rowinfo = (int2*)p;   p += (size_t)1 << 20;                   // 800 KB used
    int*   btot    = (int*)p;    p += (size_t)4 << 10;                   // 1 KB used
    int*   ebuf    = (int*)p;    p += (size_t)N_BUCKETS * CAP_E * 4;     // 8 MB
    int*   col     = (int*)p;    p += (size_t)N_BUCKETS * CAP_C * 4;     // 12.6 MB
    u16*   hbuf    = (u16*)p;    p += (size_t)13 << 20;                  // 12.8 MB used
    u16*   buf0    = (u16*)p;    p += (size_t)13 << 20;                  // chunked
    u16*   buf1    = (u16*)p;                                            // chunked

    const int gA = 2048;  // 8192 waves
    const int gM = 512;   // 2048 waves

    // ---- CSR build + chunked fp16 scale ----
    hipMemsetAsync(btot, 0, N_BUCKETS * sizeof(int), stream);
    k_bucket<<<BKT_BLOCKS, 256, 0, stream>>>(src, dst, btot, ebuf);
    k_build<<<N_BUCKETS, 1024, 0, stream>>>(btot, ebuf, col, rowinfo, dinv, z, buf0, buf1);

    // ---- 3 layers: phased agg (L2-resident chunks) + MFMA matvec ----
    k_agg<<<gA, 256, 0, stream>>>(rowinfo, col, dinv, buf0, hbuf);
    k_mv <<<gM, 256, 0, stream>>>(hbuf, W1, b1, dinv, buf1, nullptr, 1);
    k_agg<<<gA, 256, 0, stream>>>(rowinfo, col, dinv, buf1, hbuf);
    k_mv <<<gM, 256, 0, stream>>>(hbuf, W2, b2, dinv, buf0, nullptr, 1);
    k_agg<<<gA, 256, 0, stream>>>(rowinfo, col, dinv, buf0, hbuf);
    k_mv <<<gM, 256, 0, stream>>>(hbuf, W3, b3, dinv, nullptr, out, 0);
}